// Round 2
// baseline (468.908 us; speedup 1.0000x reference)
//
#include <hip/hip_runtime.h>
#include <hip/hip_bf16.h>
#include <math.h>

typedef __bf16 bf16;
typedef __bf16 bf16x8 __attribute__((ext_vector_type(8)));
typedef float floatx4 __attribute__((ext_vector_type(4)));

#define GAS __attribute__((address_space(1)))
#define LAS __attribute__((address_space(3)))

static constexpr int B_ = 16, L_ = 4096, C_ = 512;
static constexpr int M_ = B_ * L_;   // 65536 rows (b,l)
static constexpr int K_ = 3 * C_;    // 1536

// ---- K0: cast x f32 -> bf16 (8 elems/thread)
__global__ void cast_x(const float* __restrict__ x, bf16* __restrict__ xb) {
    const size_t i = ((size_t)blockIdx.x * 256 + threadIdx.x) * 8;
    floatx4 a = *(const floatx4*)(x + i);
    floatx4 b = *(const floatx4*)(x + i + 4);
    bf16x8 o;
#pragma unroll
    for (int j = 0; j < 4; ++j) { o[j] = (bf16)a[j]; o[4 + j] = (bf16)b[j]; }
    *(bf16x8*)(xb + i) = o;
}

// ---- K1: repack w_down [O][I][3] (f32) -> Wr [O][kk*512 + i] (bf16)
__global__ void repack_w(const float* __restrict__ wd, bf16* __restrict__ wr) {
    int idx = blockIdx.x * 256 + threadIdx.x;   // 512*1536 = 786432 total
    int o   = idx / K_;
    int rem = idx - o * K_;
    int kk  = rem >> 9;     // /512
    int i   = rem & 511;
    wr[idx] = (bf16)wd[o * K_ + i * 3 + kk];
}

// ---- K2: dilated-conv-as-GEMM, m97-style 128x128 tile, BK=32, 16x16x32 bf16 MFMA
// xp[b,l,o] = sum_{kk,i} x[b, l+2kk, i] * w_down[o,i,kk] + b_down[o]   (rows l>=4092 garbage, fixed later)
__global__ __launch_bounds__(256) void gemm_conv(
    const bf16* __restrict__ x, const bf16* __restrict__ wr,
    const float* __restrict__ bd, bf16* __restrict__ xp)
{
    __shared__ bf16 As[128 * 32];
    __shared__ bf16 Bs[128 * 32];

    const int tid = threadIdx.x;
    const int nb = blockIdx.x & 3;     // N=512 -> 4 n-blocks
    const int mb = blockIdx.x >> 2;    // 512 m-blocks
    const int m0 = mb * 128;
    const int n0 = nb * 128;

    const int wave = tid >> 6;
    const int lane = tid & 63;
    const int wm = wave & 1;
    const int wn = wave >> 1;
    const int tm = lane & 15;
    const int quad = lane >> 4;

    floatx4 acc[4][4];
#pragma unroll
    for (int i = 0; i < 4; ++i)
#pragma unroll
        for (int j = 0; j < 4; ++j) acc[i][j] = floatx4{0.f, 0.f, 0.f, 0.f};

    const int qa0 = tid, qa1 = tid + 256;       // two 16B stages per tile per thread
    const int rowA0 = qa0 >> 2, rowA1 = qa1 >> 2;
    const int seg = (tid & 3) << 3;             // bf16 offset within the 32-wide k-chunk

    for (int kt = 0; kt < 48; ++kt) {
        const int kk = kt >> 4;           // 0..2 (tap)
        const int i0 = (kt & 15) << 5;    // 0..480 (input-channel chunk)
        // stage A: row r of tile <- x[m0+r + 2*kk][i0 + seg .. +8]  (clamped at array end)
        {
            int sr0 = m0 + rowA0 + 2 * kk; if (sr0 > M_ - 1) sr0 = M_ - 1;
            int sr1 = m0 + rowA1 + 2 * kk; if (sr1 > M_ - 1) sr1 = M_ - 1;
            const bf16* s0 = x + (size_t)sr0 * C_ + i0 + seg;
            const bf16* s1 = x + (size_t)sr1 * C_ + i0 + seg;
            __builtin_amdgcn_global_load_lds((const GAS void*)s0, (LAS void*)(As + qa0 * 8), 16, 0, 0);
            __builtin_amdgcn_global_load_lds((const GAS void*)s1, (LAS void*)(As + qa1 * 8), 16, 0, 0);
        }
        // stage B: row n of tile <- Wr[n0+n][kk*512 + i0 + seg .. +8]  (B^T layout: [n][k])
        {
            const bf16* s0 = wr + (size_t)(n0 + rowA0) * K_ + kk * C_ + i0 + seg;
            const bf16* s1 = wr + (size_t)(n0 + rowA1) * K_ + kk * C_ + i0 + seg;
            __builtin_amdgcn_global_load_lds((const GAS void*)s0, (LAS void*)(Bs + qa0 * 8), 16, 0, 0);
            __builtin_amdgcn_global_load_lds((const GAS void*)s1, (LAS void*)(Bs + qa1 * 8), 16, 0, 0);
        }
        __syncthreads();

        bf16x8 af[4], bfr[4];
#pragma unroll
        for (int mi = 0; mi < 4; ++mi)
            af[mi] = *(const bf16x8*)(As + (wm * 64 + mi * 16 + tm) * 32 + quad * 8);
#pragma unroll
        for (int ni = 0; ni < 4; ++ni)
            bfr[ni] = *(const bf16x8*)(Bs + (wn * 64 + ni * 16 + tm) * 32 + quad * 8);
#pragma unroll
        for (int mi = 0; mi < 4; ++mi)
#pragma unroll
            for (int ni = 0; ni < 4; ++ni)
                acc[mi][ni] = __builtin_amdgcn_mfma_f32_16x16x32_bf16(af[mi], bfr[ni], acc[mi][ni], 0, 0, 0);
        __syncthreads();
    }

    // epilogue: + bias, store bf16.  C/D layout: col = lane&15, row = quad*4 + reg (m89/m91-verified)
    float bias[4];
#pragma unroll
    for (int ni = 0; ni < 4; ++ni) bias[ni] = bd[n0 + wn * 64 + ni * 16 + tm];

#pragma unroll
    for (int mi = 0; mi < 4; ++mi) {
#pragma unroll
        for (int r = 0; r < 4; ++r) {
            const int m = m0 + wm * 64 + mi * 16 + quad * 4 + r;
            bf16* dst = xp + (size_t)m * C_ + n0 + wn * 64 + tm;
#pragma unroll
            for (int ni = 0; ni < 4; ++ni)
                dst[ni * 16] = (bf16)(acc[mi][ni][r] + bias[ni]);
        }
    }
}

// ---- K3: boundary rows l in [4092,4096): xp[b][4092+j][c] = w_pad[c,:] . x[b,j,:] + b_pad[c]
__global__ void fixup(const float* __restrict__ x, const float* __restrict__ wp,
                      const float* __restrict__ bp, bf16* __restrict__ xp)
{
    const int b = blockIdx.x >> 2;
    const int j = blockIdx.x & 3;
    __shared__ float xrow[C_];
    for (int i = threadIdx.x; i < C_; i += 256)
        xrow[i] = x[(size_t)(b * L_ + j) * C_ + i];
    __syncthreads();
    for (int c = threadIdx.x; c < C_; c += 256) {
        const float* w = wp + (size_t)c * C_;
        float acc = 0.f;
#pragma unroll 4
        for (int i = 0; i < C_; i += 4) {
            floatx4 wv = *(const floatx4*)(w + i);
#pragma unroll
            for (int u = 0; u < 4; ++u) acc += wv[u] * xrow[i + u];
        }
        xp[(size_t)(b * L_ + 4092 + j) * C_ + c] = (bf16)(acc + bp[c]);
    }
}

// ---- K4: per-channel sum / sumsq over all 65536 rows
__global__ void stats_reduce(const bf16* __restrict__ xp, float* __restrict__ sums) {
    const int c = threadIdx.x * 2;        // 2 channels per thread
    const size_t r0 = (size_t)blockIdx.x * 256;
    float s0 = 0.f, s1 = 0.f, q0 = 0.f, q1 = 0.f;
    for (int r = 0; r < 256; ++r) {
        const bf16* p = xp + (r0 + r) * C_ + c;
        float v0 = (float)p[0], v1 = (float)p[1];
        s0 += v0; q0 += v0 * v0;
        s1 += v1; q1 += v1 * v1;
    }
    atomicAdd(&sums[c], s0);
    atomicAdd(&sums[c + 1], s1);
    atomicAdd(&sums[C_ + c], q0);
    atomicAdd(&sums[C_ + c + 1], q1);
}

// ---- K5: fold BN stats + gamma/beta into scale/shift
__global__ void finalize_stats(const float* __restrict__ sums, const float* __restrict__ gamma,
                               const float* __restrict__ beta, float* __restrict__ ss) {
    const int c = threadIdx.x;            // 512 threads
    const float invn = 1.0f / 65536.0f;
    float mean = sums[c] * invn;
    float var  = sums[C_ + c] * invn - mean * mean;
    float scale = gamma[c] * rsqrtf(var + 1e-5f);
    ss[c] = scale;
    ss[C_ + c] = beta[c] - mean * scale;
}

// ---- K6: BN -> ELU -> +residual -> maxpool(3, stride2, pad1) -> [B, L/2, C] f32
__global__ void final_pool(const bf16* __restrict__ xp, const float* __restrict__ x,
                           const float* __restrict__ ss, float* __restrict__ out)
{
    const int gid = blockIdx.x * 256 + threadIdx.x;  // B * 2048 * 64 groups of 8 ch
    const int cg = gid & 63;
    const int t  = (gid >> 6) & 2047;
    const int b  = gid >> 17;
    const int c0 = cg << 3;

    float sc[8], sh[8];
#pragma unroll
    for (int j = 0; j < 8; ++j) { sc[j] = ss[c0 + j]; sh[j] = ss[C_ + c0 + j]; }

    float best[8];
#pragma unroll
    for (int j = 0; j < 8; ++j) best[j] = -INFINITY;

#pragma unroll
    for (int dl = -1; dl <= 1; ++dl) {
        const int l = 2 * t + dl;
        if (l < 0) continue;                        // right edge never exceeds 4095
        const size_t off = (size_t)(b * L_ + l) * C_ + c0;
        bf16x8 xpv = *(const bf16x8*)(xp + off);
        floatx4 xv0 = *(const floatx4*)(x + off);
        floatx4 xv1 = *(const floatx4*)(x + off + 4);
#pragma unroll
        for (int j = 0; j < 8; ++j) {
            float z = sc[j] * (float)xpv[j] + sh[j];
            float y = (z > 0.f) ? z : (expf(z) - 1.f);
            y += (j < 4) ? xv0[j] : xv1[j - 4];
            best[j] = fmaxf(best[j], y);
        }
    }
    floatx4 o0, o1;
#pragma unroll
    for (int j = 0; j < 4; ++j) { o0[j] = best[j]; o1[j] = best[4 + j]; }
    *(floatx4*)(out + (size_t)gid * 8) = o0;
    *(floatx4*)(out + (size_t)gid * 8 + 4) = o1;
}

extern "C" void kernel_launch(void* const* d_in, const int* in_sizes, int n_in,
                              void* d_out, int out_size, void* d_ws, size_t ws_size,
                              hipStream_t stream)
{
    const float* x      = (const float*)d_in[0];
    const float* w_down = (const float*)d_in[1];
    const float* b_down = (const float*)d_in[2];
    const float* w_pad  = (const float*)d_in[3];
    const float* b_pad  = (const float*)d_in[4];
    const float* gamma  = (const float*)d_in[5];
    const float* beta   = (const float*)d_in[6];
    float* out = (float*)d_out;

    char* ws = (char*)d_ws;
    bf16*  xb   = (bf16*)ws;                                        // 64 MiB  [B*L][C] bf16 copy of x
    bf16*  xp   = (bf16*)(ws + (size_t)M_ * C_ * 2);                // 64 MiB  [B*L][C]
    bf16*  wr   = (bf16*)(ws + (size_t)M_ * C_ * 4);                // 1.5 MiB [O][K]
    float* sums = (float*)(ws + (size_t)M_ * C_ * 4 + (size_t)C_ * K_ * 2);  // 1024 f32
    float* ss   = sums + 2 * C_;                                    // 1024 f32 scale/shift

    hipMemsetAsync(sums, 0, 2 * C_ * sizeof(float), stream);
    cast_x<<<dim3(M_ * C_ / (256 * 8)), dim3(256), 0, stream>>>(x, xb);
    repack_w<<<dim3(3072), dim3(256), 0, stream>>>(w_down, wr);
    gemm_conv<<<dim3(2048), dim3(256), 0, stream>>>(xb, wr, b_down, xp);
    fixup<<<dim3(64), dim3(256), 0, stream>>>(x, w_pad, b_pad, xp);
    stats_reduce<<<dim3(256), dim3(256), 0, stream>>>(xp, sums);
    finalize_stats<<<dim3(1), dim3(512), 0, stream>>>(sums, gamma, beta, ss);
    final_pool<<<dim3(8192), dim3(256), 0, stream>>>(xp, x, ss, out);
}

// Round 3
// 430.993 us; speedup vs baseline: 1.0880x; 1.0880x over previous
//
#include <hip/hip_runtime.h>
#include <hip/hip_bf16.h>
#include <math.h>

typedef __bf16 bf16;
typedef __bf16 bf16x8 __attribute__((ext_vector_type(8)));
typedef float floatx4 __attribute__((ext_vector_type(4)));

#define GAS __attribute__((address_space(1)))
#define LAS __attribute__((address_space(3)))

static constexpr int B_ = 16, L_ = 4096, C_ = 512;
static constexpr int M_ = B_ * L_;   // 65536 rows (b,l)
static constexpr int K_ = 3 * C_;    // 1536

// ---- K0: cast x f32 -> bf16 (8 elems/thread)
__global__ void cast_x(const float* __restrict__ x, bf16* __restrict__ xb) {
    const size_t i = ((size_t)blockIdx.x * 256 + threadIdx.x) * 8;
    floatx4 a = *(const floatx4*)(x + i);
    floatx4 b = *(const floatx4*)(x + i + 4);
    bf16x8 o;
#pragma unroll
    for (int j = 0; j < 4; ++j) { o[j] = (bf16)a[j]; o[4 + j] = (bf16)b[j]; }
    *(bf16x8*)(xb + i) = o;
}

// ---- K1: repack w_down [O][I][3] (f32) -> Wr [O][kk*512 + i] (bf16)
__global__ void repack_w(const float* __restrict__ wd, bf16* __restrict__ wr) {
    int idx = blockIdx.x * 256 + threadIdx.x;   // 512*1536 = 786432 total
    int o   = idx / K_;
    int rem = idx - o * K_;
    int kk  = rem >> 9;     // /512
    int i   = rem & 511;
    wr[idx] = (bf16)wd[o * K_ + i * 3 + kk];
}

// ---- K2: dilated-conv-as-GEMM. 128x128 tile, BK=64, XCD swizzle, LDS XOR swizzle,
//          fused per-channel sum/sumsq (boundary rows l>=4092 masked; fixup adds them).
__global__ __launch_bounds__(256) void gemm_conv(
    const bf16* __restrict__ x, const bf16* __restrict__ wr,
    const float* __restrict__ bd, bf16* __restrict__ xp, float* __restrict__ sums)
{
    __shared__ bf16 As[128 * 64];   // 16 KB
    __shared__ bf16 Bs[128 * 64];   // 16 KB

    const int tid = threadIdx.x;
    // XCD-aware swizzle: the 4 n-blocks of one m-tile land on the same XCD (bid%8).
    const int u   = blockIdx.x;
    const int mb  = (u & 7) + 8 * (u >> 5);    // (u>>3)>>2
    const int nb  = (u >> 3) & 3;
    const int m0  = mb * 128;
    const int n0  = nb * 128;

    const int wave = tid >> 6;
    const int lane = tid & 63;
    const int wm = wave & 1;
    const int wn = wave >> 1;
    const int tm = lane & 15;
    const int quad = lane >> 4;

    floatx4 acc[4][4];
#pragma unroll
    for (int i = 0; i < 4; ++i)
#pragma unroll
        for (int j = 0; j < 4; ++j) acc[i][j] = floatx4{0.f, 0.f, 0.f, 0.f};

    // staging map: load j covers LDS chunk qa = tid + 256j (16 B each);
    // row = qa>>3, landing chunk p = qa&7, SOURCE chunk sc = p ^ (row&7)  (XOR swizzle)
    int srow[4], ssc[4];
#pragma unroll
    for (int j = 0; j < 4; ++j) {
        const int qa = tid + 256 * j;
        srow[j] = qa >> 3;
        ssc[j]  = (qa & 7) ^ (srow[j] & 7);
    }

    for (int kt = 0; kt < 24; ++kt) {
        const int kk = kt >> 3;           // tap 0..2
        const int i0 = (kt & 7) << 6;     // input-channel base 0..448
#pragma unroll
        for (int j = 0; j < 4; ++j) {
            int sr = m0 + srow[j] + 2 * kk; if (sr > M_ - 1) sr = M_ - 1;
            const bf16* sa = x + (size_t)sr * C_ + i0 + ssc[j] * 8;
            __builtin_amdgcn_global_load_lds((const GAS void*)sa,
                (LAS void*)(As + (tid + 256 * j) * 8), 16, 0, 0);
            const bf16* sb = wr + (size_t)(n0 + srow[j]) * K_ + kk * C_ + i0 + ssc[j] * 8;
            __builtin_amdgcn_global_load_lds((const GAS void*)sb,
                (LAS void*)(Bs + (tid + 256 * j) * 8), 16, 0, 0);
        }
        __syncthreads();

#pragma unroll
        for (int ksel = 0; ksel < 2; ++ksel) {   // k-halves 0..31, 32..63
            const int scb = ksel * 4 + quad;     // needed source chunk
            bf16x8 af[4], bfr[4];
#pragma unroll
            for (int mi = 0; mi < 4; ++mi) {
                const int r = wm * 64 + mi * 16 + tm;
                af[mi] = *(const bf16x8*)(As + r * 64 + ((scb ^ (r & 7)) << 3));
            }
#pragma unroll
            for (int ni = 0; ni < 4; ++ni) {
                const int r = wn * 64 + ni * 16 + tm;
                bfr[ni] = *(const bf16x8*)(Bs + r * 64 + ((scb ^ (r & 7)) << 3));
            }
#pragma unroll
            for (int mi = 0; mi < 4; ++mi)
#pragma unroll
                for (int ni = 0; ni < 4; ++ni)
                    acc[mi][ni] = __builtin_amdgcn_mfma_f32_16x16x32_bf16(af[mi], bfr[ni], acc[mi][ni], 0, 0, 0);
        }
        __syncthreads();
    }

    // epilogue: + bias, store bf16, fused stats. C/D: col=lane&15, row=quad*4+reg.
    float bias[4];
#pragma unroll
    for (int ni = 0; ni < 4; ++ni) bias[ni] = bd[n0 + wn * 64 + ni * 16 + tm];

    float s[4] = {0.f, 0.f, 0.f, 0.f}, q[4] = {0.f, 0.f, 0.f, 0.f};
#pragma unroll
    for (int mi = 0; mi < 4; ++mi) {
#pragma unroll
        for (int r = 0; r < 4; ++r) {
            const int m = m0 + wm * 64 + mi * 16 + quad * 4 + r;
            const bool valid = (m & (L_ - 1)) < L_ - 4;   // exclude garbage boundary rows
            bf16* dst = xp + (size_t)m * C_ + n0 + wn * 64 + tm;
#pragma unroll
            for (int ni = 0; ni < 4; ++ni) {
                const float v = acc[mi][ni][r] + bias[ni];
                dst[ni * 16] = (bf16)v;
                if (valid) { s[ni] += v; q[ni] += v * v; }
            }
        }
    }
#pragma unroll
    for (int ni = 0; ni < 4; ++ni) {
        float sv = s[ni], qv = q[ni];
        sv += __shfl_xor(sv, 16); sv += __shfl_xor(sv, 32);
        qv += __shfl_xor(qv, 16); qv += __shfl_xor(qv, 32);
        if (quad == 0) {
            const int c = n0 + wn * 64 + ni * 16 + tm;
            atomicAdd(&sums[c], sv);
            atomicAdd(&sums[C_ + c], qv);
        }
    }
}

// ---- K3: boundary rows l in [4092,4096): xp = w_pad . x + b_pad, plus their stats
__global__ void fixup(const float* __restrict__ x, const float* __restrict__ wp,
                      const float* __restrict__ bp, bf16* __restrict__ xp,
                      float* __restrict__ sums)
{
    const int b = blockIdx.x >> 2;
    const int j = blockIdx.x & 3;
    __shared__ float xrow[C_];
    for (int i = threadIdx.x; i < C_; i += 256)
        xrow[i] = x[(size_t)(b * L_ + j) * C_ + i];
    __syncthreads();
    for (int c = threadIdx.x; c < C_; c += 256) {
        const float* w = wp + (size_t)c * C_;
        float acc = 0.f;
#pragma unroll 4
        for (int i = 0; i < C_; i += 4) {
            floatx4 wv = *(const floatx4*)(w + i);
#pragma unroll
            for (int u = 0; u < 4; ++u) acc += wv[u] * xrow[i + u];
        }
        const float v = acc + bp[c];
        xp[(size_t)(b * L_ + 4092 + j) * C_ + c] = (bf16)v;
        atomicAdd(&sums[c], v);
        atomicAdd(&sums[C_ + c], v * v);
    }
}

// ---- K5: fold BN stats + gamma/beta into scale/shift
__global__ void finalize_stats(const float* __restrict__ sums, const float* __restrict__ gamma,
                               const float* __restrict__ beta, float* __restrict__ ss) {
    const int c = threadIdx.x;            // 512 threads
    const float invn = 1.0f / 65536.0f;
    float mean = sums[c] * invn;
    float var  = sums[C_ + c] * invn - mean * mean;
    float scale = gamma[c] * rsqrtf(var + 1e-5f);
    ss[c] = scale;
    ss[C_ + c] = beta[c] - mean * scale;
}

// ---- K6: BN -> ELU -> +residual(bf16) -> maxpool(3, stride2, pad1) -> [B, L/2, C] f32
__global__ void final_pool(const bf16* __restrict__ xp, const bf16* __restrict__ xb,
                           const float* __restrict__ ss, float* __restrict__ out)
{
    const int gid = blockIdx.x * 256 + threadIdx.x;  // B * 2048 * 64 groups of 8 ch
    const int cg = gid & 63;
    const int t  = (gid >> 6) & 2047;
    const int b  = gid >> 17;
    const int c0 = cg << 3;

    float sc[8], sh[8];
#pragma unroll
    for (int j = 0; j < 8; ++j) { sc[j] = ss[c0 + j]; sh[j] = ss[C_ + c0 + j]; }

    float best[8];
#pragma unroll
    for (int j = 0; j < 8; ++j) best[j] = -INFINITY;

#pragma unroll
    for (int dl = -1; dl <= 1; ++dl) {
        const int l = 2 * t + dl;
        if (l < 0) continue;                        // right edge never exceeds 4095
        const size_t off = (size_t)(b * L_ + l) * C_ + c0;
        bf16x8 xpv = *(const bf16x8*)(xp + off);
        bf16x8 xv  = *(const bf16x8*)(xb + off);
#pragma unroll
        for (int j = 0; j < 8; ++j) {
            float z = sc[j] * (float)xpv[j] + sh[j];
            float y = (z > 0.f) ? z : (expf(z) - 1.f);
            y += (float)xv[j];
            best[j] = fmaxf(best[j], y);
        }
    }
    floatx4 o0, o1;
#pragma unroll
    for (int j = 0; j < 4; ++j) { o0[j] = best[j]; o1[j] = best[4 + j]; }
    *(floatx4*)(out + (size_t)gid * 8) = o0;
    *(floatx4*)(out + (size_t)gid * 8 + 4) = o1;
}

extern "C" void kernel_launch(void* const* d_in, const int* in_sizes, int n_in,
                              void* d_out, int out_size, void* d_ws, size_t ws_size,
                              hipStream_t stream)
{
    const float* x      = (const float*)d_in[0];
    const float* w_down = (const float*)d_in[1];
    const float* b_down = (const float*)d_in[2];
    const float* w_pad  = (const float*)d_in[3];
    const float* b_pad  = (const float*)d_in[4];
    const float* gamma  = (const float*)d_in[5];
    const float* beta   = (const float*)d_in[6];
    float* out = (float*)d_out;

    char* ws = (char*)d_ws;
    bf16*  xb   = (bf16*)ws;                                        // 64 MiB  [B*L][C] bf16 copy of x
    bf16*  xp   = (bf16*)(ws + (size_t)M_ * C_ * 2);                // 64 MiB  [B*L][C]
    bf16*  wr   = (bf16*)(ws + (size_t)M_ * C_ * 4);                // 1.5 MiB [O][K]
    float* sums = (float*)(ws + (size_t)M_ * C_ * 4 + (size_t)C_ * K_ * 2);  // 1024 f32
    float* ss   = sums + 2 * C_;                                    // 1024 f32 scale/shift

    hipMemsetAsync(sums, 0, 2 * C_ * sizeof(float), stream);
    cast_x<<<dim3(M_ * C_ / (256 * 8)), dim3(256), 0, stream>>>(x, xb);
    repack_w<<<dim3(3072), dim3(256), 0, stream>>>(w_down, wr);
    gemm_conv<<<dim3(2048), dim3(256), 0, stream>>>(xb, wr, b_down, xp, sums);
    fixup<<<dim3(64), dim3(256), 0, stream>>>(x, w_pad, b_pad, xp, sums);
    finalize_stats<<<dim3(1), dim3(512), 0, stream>>>(sums, gamma, beta, ss);
    final_pool<<<dim3(8192), dim3(256), 0, stream>>>(xp, xb, ss, out);
}

// Round 4
// 416.833 us; speedup vs baseline: 1.1249x; 1.0340x over previous
//
#include <hip/hip_runtime.h>
#include <hip/hip_bf16.h>
#include <math.h>

typedef __bf16 bf16;
typedef __bf16 bf16x8 __attribute__((ext_vector_type(8)));
typedef float floatx4 __attribute__((ext_vector_type(4)));

#define GAS __attribute__((address_space(1)))
#define LAS __attribute__((address_space(3)))

static constexpr int B_ = 16, L_ = 4096, C_ = 512;
static constexpr int M_ = B_ * L_;   // 65536 rows (b,l)
static constexpr int K_ = 3 * C_;    // 1536

// ---- K1: fused prep. blocks [0,16384): cast x f32->bf16; [16384,19456): repack w_down.
__global__ void prep(const float* __restrict__ x, bf16* __restrict__ xb,
                     const float* __restrict__ wd, bf16* __restrict__ wr) {
    if (blockIdx.x < 16384) {
        const size_t i = ((size_t)blockIdx.x * 256 + threadIdx.x) * 8;
        floatx4 a = *(const floatx4*)(x + i);
        floatx4 b = *(const floatx4*)(x + i + 4);
        bf16x8 o;
#pragma unroll
        for (int j = 0; j < 4; ++j) { o[j] = (bf16)a[j]; o[4 + j] = (bf16)b[j]; }
        *(bf16x8*)(xb + i) = o;
    } else {
        int idx = (blockIdx.x - 16384) * 256 + threadIdx.x;   // 512*1536 total
        int o   = idx / K_;
        int rem = idx - o * K_;
        int kk  = rem >> 9;
        int i   = rem & 511;
        wr[idx] = (bf16)wd[o * K_ + i * 3 + kk];
    }
}

// ---- K2: dilated-conv-as-GEMM. 256x256 tile, 512 thr, BK=64, XOR swizzle, fused stats.
// L2-BW model: 64KB staged / 512 MFMA per iter = 128 B/MFMA (half of round-3's 256).
__global__ __launch_bounds__(512, 2) void gemm_conv(
    const bf16* __restrict__ x, const bf16* __restrict__ wr,
    const float* __restrict__ bd, bf16* __restrict__ xp, float* __restrict__ sums)
{
    __shared__ bf16 As[256 * 64];   // 32 KB
    __shared__ bf16 Bs[256 * 64];   // 32 KB

    const int tid = threadIdx.x;
    // XCD swizzle: the 2 n-blocks of one m-tile land on the same XCD (u%8 == (u+8)%8).
    const int u   = blockIdx.x;           // 0..511
    const int mb  = (u & 7) + 8 * (u >> 4);
    const int nb  = (u >> 3) & 1;
    const int m0  = mb * 256;
    const int n0  = nb * 256;

    const int wave = tid >> 6;
    const int lane = tid & 63;
    const int wm = wave & 3;              // 4 m-strips of 64
    const int wn = wave >> 2;             // 2 n-strips of 128
    const int tm = lane & 15;
    const int quad = lane >> 4;

    floatx4 acc[4][8];
#pragma unroll
    for (int i = 0; i < 4; ++i)
#pragma unroll
        for (int j = 0; j < 8; ++j) acc[i][j] = floatx4{0.f, 0.f, 0.f, 0.f};

    // staging map: chunk qa = tid + 512j (16B each); row = qa>>3, landing chunk p = qa&7,
    // SOURCE chunk = p ^ (row&7)  (XOR swizzle; reads recompute the same XOR)
    int srow[4], ssc[4];
#pragma unroll
    for (int j = 0; j < 4; ++j) {
        const int qa = tid + 512 * j;
        srow[j] = qa >> 3;
        ssc[j]  = (qa & 7) ^ (srow[j] & 7);
    }

    for (int kt = 0; kt < 24; ++kt) {
        const int kk = kt >> 3;           // tap 0..2
        const int i0 = (kt & 7) << 6;     // input-channel base 0..448
#pragma unroll
        for (int j = 0; j < 4; ++j) {
            int sr = m0 + srow[j] + 2 * kk; if (sr > M_ - 1) sr = M_ - 1;
            const bf16* sa = x + (size_t)sr * C_ + i0 + ssc[j] * 8;
            __builtin_amdgcn_global_load_lds((const GAS void*)sa,
                (LAS void*)(As + (tid + 512 * j) * 8), 16, 0, 0);
            const bf16* sb = wr + (size_t)(n0 + srow[j]) * K_ + kk * C_ + i0 + ssc[j] * 8;
            __builtin_amdgcn_global_load_lds((const GAS void*)sb,
                (LAS void*)(Bs + (tid + 512 * j) * 8), 16, 0, 0);
        }
        __syncthreads();

#pragma unroll
        for (int ksel = 0; ksel < 2; ++ksel) {   // k-halves 0..31, 32..63
            const int xo = ((ksel * 4 + quad) ^ (tm & 7)) << 3;  // XOR'd chunk offset (elems)
            bf16x8 af[4], bfr[8];
#pragma unroll
            for (int mi = 0; mi < 4; ++mi) {
                const int r = wm * 64 + mi * 16 + tm;
                af[mi] = *(const bf16x8*)(As + r * 64 + xo);
            }
#pragma unroll
            for (int ni = 0; ni < 8; ++ni) {
                const int r = wn * 128 + ni * 16 + tm;
                bfr[ni] = *(const bf16x8*)(Bs + r * 64 + xo);
            }
#pragma unroll
            for (int mi = 0; mi < 4; ++mi)
#pragma unroll
                for (int ni = 0; ni < 8; ++ni)
                    acc[mi][ni] = __builtin_amdgcn_mfma_f32_16x16x32_bf16(af[mi], bfr[ni], acc[mi][ni], 0, 0, 0);
        }
        __syncthreads();
    }

    // epilogue: + bias, store bf16, fused stats. C/D: col=lane&15, row=quad*4+reg.
    float bias[8];
#pragma unroll
    for (int ni = 0; ni < 8; ++ni) bias[ni] = bd[n0 + wn * 128 + ni * 16 + tm];

    float s[8] = {0,0,0,0,0,0,0,0}, q[8] = {0,0,0,0,0,0,0,0};
#pragma unroll
    for (int mi = 0; mi < 4; ++mi) {
#pragma unroll
        for (int r = 0; r < 4; ++r) {
            const int m = m0 + wm * 64 + mi * 16 + quad * 4 + r;
            const bool valid = (m & (L_ - 1)) < L_ - 4;   // exclude garbage boundary rows
            bf16* dst = xp + (size_t)m * C_ + n0 + wn * 128 + tm;
#pragma unroll
            for (int ni = 0; ni < 8; ++ni) {
                const float v = acc[mi][ni][r] + bias[ni];
                dst[ni * 16] = (bf16)v;
                if (valid) { s[ni] += v; q[ni] += v * v; }
            }
        }
    }
#pragma unroll
    for (int ni = 0; ni < 8; ++ni) {
        float sv = s[ni], qv = q[ni];
        sv += __shfl_xor(sv, 16); sv += __shfl_xor(sv, 32);
        qv += __shfl_xor(qv, 16); qv += __shfl_xor(qv, 32);
        if (quad == 0) {
            const int c = n0 + wn * 128 + ni * 16 + tm;
            atomicAdd(&sums[c], sv);
            atomicAdd(&sums[C_ + c], qv);
        }
    }
}

// ---- K3: boundary rows l in [4092,4096): xp = w_pad . x + b_pad, plus their stats
__global__ void fixup(const float* __restrict__ x, const float* __restrict__ wp,
                      const float* __restrict__ bp, bf16* __restrict__ xp,
                      float* __restrict__ sums)
{
    const int b = blockIdx.x >> 2;
    const int j = blockIdx.x & 3;
    __shared__ float xrow[C_];
    for (int i = threadIdx.x; i < C_; i += 256)
        xrow[i] = x[(size_t)(b * L_ + j) * C_ + i];
    __syncthreads();
    for (int c = threadIdx.x; c < C_; c += 256) {
        const float* w = wp + (size_t)c * C_;
        float acc = 0.f;
#pragma unroll 4
        for (int i = 0; i < C_; i += 4) {
            floatx4 wv = *(const floatx4*)(w + i);
#pragma unroll
            for (int u = 0; u < 4; ++u) acc += wv[u] * xrow[i + u];
        }
        const float v = acc + bp[c];
        xp[(size_t)(b * L_ + 4092 + j) * C_ + c] = (bf16)v;
        atomicAdd(&sums[c], v);
        atomicAdd(&sums[C_ + c], v * v);
    }
}

// ---- K4: BN(from raw sums) -> ELU -> +residual(bf16) -> maxpool(3,2,pad1) -> [B,L/2,C] f32
__global__ void final_pool(const bf16* __restrict__ xp, const bf16* __restrict__ xb,
                           const float* __restrict__ sums, const float* __restrict__ gamma,
                           const float* __restrict__ beta, float* __restrict__ out)
{
    const int gid = blockIdx.x * 256 + threadIdx.x;  // B * 2048 * 64 groups of 8 ch
    const int cg = gid & 63;
    const int t  = (gid >> 6) & 2047;
    const int b  = gid >> 17;
    const int c0 = cg << 3;

    float sc[8], sh[8];
    const float invn = 1.0f / 65536.0f;
#pragma unroll
    for (int j = 0; j < 8; ++j) {
        const int c = c0 + j;
        float mean = sums[c] * invn;
        float var  = sums[C_ + c] * invn - mean * mean;
        float scale = gamma[c] * rsqrtf(var + 1e-5f);
        sc[j] = scale;
        sh[j] = beta[c] - mean * scale;
    }

    float best[8];
#pragma unroll
    for (int j = 0; j < 8; ++j) best[j] = -INFINITY;

#pragma unroll
    for (int dl = -1; dl <= 1; ++dl) {
        const int l = 2 * t + dl;
        if (l < 0) continue;                        // right edge never exceeds 4095
        const size_t off = (size_t)(b * L_ + l) * C_ + c0;
        bf16x8 xpv = *(const bf16x8*)(xp + off);
        bf16x8 xv  = *(const bf16x8*)(xb + off);
#pragma unroll
        for (int j = 0; j < 8; ++j) {
            float z = sc[j] * (float)xpv[j] + sh[j];
            float y = (z > 0.f) ? z : (__expf(z) - 1.f);
            y += (float)xv[j];
            best[j] = fmaxf(best[j], y);
        }
    }
    floatx4 o0, o1;
#pragma unroll
    for (int j = 0; j < 4; ++j) { o0[j] = best[j]; o1[j] = best[4 + j]; }
    *(floatx4*)(out + (size_t)gid * 8) = o0;
    *(floatx4*)(out + (size_t)gid * 8 + 4) = o1;
}

extern "C" void kernel_launch(void* const* d_in, const int* in_sizes, int n_in,
                              void* d_out, int out_size, void* d_ws, size_t ws_size,
                              hipStream_t stream)
{
    const float* x      = (const float*)d_in[0];
    const float* w_down = (const float*)d_in[1];
    const float* b_down = (const float*)d_in[2];
    const float* w_pad  = (const float*)d_in[3];
    const float* b_pad  = (const float*)d_in[4];
    const float* gamma  = (const float*)d_in[5];
    const float* beta   = (const float*)d_in[6];
    float* out = (float*)d_out;

    char* ws = (char*)d_ws;
    bf16*  xb   = (bf16*)ws;                                        // 64 MiB  [B*L][C] bf16 copy of x
    bf16*  xp   = (bf16*)(ws + (size_t)M_ * C_ * 2);                // 64 MiB  [B*L][C]
    bf16*  wr   = (bf16*)(ws + (size_t)M_ * C_ * 4);                // 1.5 MiB [O][K]
    float* sums = (float*)(ws + (size_t)M_ * C_ * 4 + (size_t)C_ * K_ * 2);  // 1024 f32

    hipMemsetAsync(sums, 0, 2 * C_ * sizeof(float), stream);
    prep<<<dim3(16384 + 3072), dim3(256), 0, stream>>>(x, xb, w_down, wr);
    gemm_conv<<<dim3(512), dim3(512), 0, stream>>>(xb, wr, b_down, xp, sums);
    fixup<<<dim3(64), dim3(256), 0, stream>>>(x, w_pad, b_pad, xp, sums);
    final_pool<<<dim3(8192), dim3(256), 0, stream>>>(xp, xb, sums, gamma, beta, out);
}